// Round 1
// baseline (400.345 us; speedup 1.0000x reference)
//
#include <hip/hip_runtime.h>

typedef unsigned short u16;
typedef __attribute__((ext_vector_type(8))) short bf16x8;
typedef __attribute__((ext_vector_type(4))) float f32x4;

__device__ inline u16 f2bf(float f) {
    union { float f; unsigned u; } v; v.f = f;
    unsigned r = v.u + 0x7fffu + ((v.u >> 16) & 1u);   // round-to-nearest-even
    return (u16)(r >> 16);
}
__device__ inline float bf2f(u16 h) {
    union { unsigned u; float f; } v; v.u = ((unsigned)h) << 16; return v.f;
}

#define LDSS 40   // LDS row stride (elements) for 32-wide k tiles, +8 pad

// C[m,n] = sum_k A[m,k] * W[n,k] + bias[n]   (torch Linear, NT GEMM)
// EPI==0: write bf16 with head-permute layout out[((b*16+h)*1024+l)*64+hd]
// EPI==1: write fp32 row-major out[m*N+n]
template<bool A_IS_F32, int EPI>
__global__ __launch_bounds__(256) void gemm_nt(const void* __restrict__ Av,
                                               const float* __restrict__ W,
                                               const float* __restrict__ bias,
                                               void* __restrict__ outv,
                                               int M, int N, int K)
{
    __shared__ u16 lA[128 * LDSS];
    __shared__ u16 lB[128 * LDSS];
    const int t = threadIdx.x;
    const int wave = t >> 6, lane = t & 63;
    const int quad = lane >> 4, l16 = lane & 15;
    const int mtile = blockIdx.y, ntile = blockIdx.x;
    const int wm = (wave >> 1) * 64, wn = (wave & 1) * 64;
    const int rowsA = mtile * 128, rowsB = ntile * 128;

    f32x4 acc[4][4] = {};

    for (int kb = 0; kb < K; kb += 32) {
        // ---- stage A tile [128 x 32] -> bf16 LDS ----
        if constexpr (A_IS_F32) {
            const float* A = (const float*)Av;
#pragma unroll
            for (int i = 0; i < 4; i++) {
                int idx = t + i * 256;
                int r = idx >> 3, c4 = idx & 7;
                float4 v = *(const float4*)(A + (size_t)(rowsA + r) * K + kb + c4 * 4);
                u16* dst = lA + r * LDSS + c4 * 4;
                dst[0] = f2bf(v.x); dst[1] = f2bf(v.y);
                dst[2] = f2bf(v.z); dst[3] = f2bf(v.w);
            }
        } else {
            const u16* A = (const u16*)Av;
#pragma unroll
            for (int i = 0; i < 2; i++) {
                int idx = t + i * 256;
                int r = idx >> 2, c8 = idx & 3;
                bf16x8 v = *(const bf16x8*)(A + (size_t)(rowsA + r) * K + kb + c8 * 8);
                *(bf16x8*)(lA + r * LDSS + c8 * 8) = v;
            }
        }
        // ---- stage B tile (W rows) [128 x 32] -> bf16 LDS ----
#pragma unroll
        for (int i = 0; i < 4; i++) {
            int idx = t + i * 256;
            int r = idx >> 3, c4 = idx & 7;
            float4 v = *(const float4*)(W + (size_t)(rowsB + r) * K + kb + c4 * 4);
            u16* dst = lB + r * LDSS + c4 * 4;
            dst[0] = f2bf(v.x); dst[1] = f2bf(v.y);
            dst[2] = f2bf(v.z); dst[3] = f2bf(v.w);
        }
        __syncthreads();

        bf16x8 af[4], bfr[4];
#pragma unroll
        for (int i = 0; i < 4; i++)
            af[i] = *(const bf16x8*)(lA + (wm + i * 16 + l16) * LDSS + quad * 8);
#pragma unroll
        for (int i = 0; i < 4; i++)
            bfr[i] = *(const bf16x8*)(lB + (wn + i * 16 + l16) * LDSS + quad * 8);
#pragma unroll
        for (int mi = 0; mi < 4; mi++)
#pragma unroll
            for (int ni = 0; ni < 4; ni++)
                acc[mi][ni] = __builtin_amdgcn_mfma_f32_16x16x32_bf16(af[mi], bfr[ni], acc[mi][ni], 0, 0, 0);
        __syncthreads();
    }

    // ---- epilogue ----
#pragma unroll
    for (int mi = 0; mi < 4; mi++) {
#pragma unroll
        for (int ni = 0; ni < 4; ni++) {
            int ncol = ntile * 128 + wn + ni * 16 + l16;
            float bv = bias[ncol];
#pragma unroll
            for (int r = 0; r < 4; r++) {
                int mrow = mtile * 128 + wm + mi * 16 + quad * 4 + r;
                float val = acc[mi][ni][r] + bv;
                if constexpr (EPI == 0) {
                    int b = mrow >> 10, l = mrow & 1023;
                    int h = ncol >> 6, hd = ncol & 63;
                    ((u16*)outv)[(((size_t)(b * 16 + h) * 1024 + l) << 6) + hd] = f2bf(val);
                } else {
                    ((float*)outv)[(size_t)mrow * N + ncol] = val;
                }
            }
        }
    }
}

// Flash attention. qh/kh/vh: bf16 [B*H][L][64]. y out: bf16 [4096][1024]
// block = 256 threads (4 waves); grid = B*H*(L/64); wave w owns 16 q rows.
__global__ __launch_bounds__(256) void attn_kernel(const u16* __restrict__ qh,
                                                   const u16* __restrict__ kh,
                                                   const u16* __restrict__ vh,
                                                   u16* __restrict__ y)
{
    constexpr int L = 1024, HD = 64;
    __shared__ u16 sK[32 * 72];        // [krow][d], stride 72
    __shared__ u16 sVT[64 * 40];       // [d][krow], stride 40
    __shared__ u16 sP[4 * 16 * 40];    // per-wave [qr][k], stride 40

    const int t = threadIdx.x;
    const int wave = t >> 6, lane = t & 63;
    const int quad = lane >> 4, l16 = lane & 15;
    const int bid = blockIdx.x;
    const int qt = bid & 15;           // q-tile of 64 within L
    const int bh = bid >> 4;           // b*16 + h
    const size_t base = (size_t)bh * L * HD;
    const int qbase = qt * 64 + wave * 16;

    // Q fragments (held for whole kernel)
    bf16x8 aq0 = *(const bf16x8*)(qh + base + (size_t)(qbase + l16) * HD + quad * 8);
    bf16x8 aq1 = *(const bf16x8*)(qh + base + (size_t)(qbase + l16) * HD + 32 + quad * 8);

    f32x4 o[4] = {};          // o[nt]: cols d = nt*16 + l16, rows quad*4+r
    float mrow[4], lrow[4];
#pragma unroll
    for (int r = 0; r < 4; r++) { mrow[r] = -INFINITY; lrow[r] = 0.f; }

    const int nkt = qt * 2 + 2;        // 32-row k-tiles covering [0, qt*64+64)
    const float scale = 0.125f;        // 1/sqrt(64)

    for (int kb = 0; kb < nkt; kb++) {
        const int krow0 = kb * 32;
        // ---- stage K [32x64] and V^T [64x32] ----
        {
            int r = t >> 3, c8 = t & 7;
            bf16x8 vk = *(const bf16x8*)(kh + base + (size_t)(krow0 + r) * HD + c8 * 8);
            *(bf16x8*)(sK + r * 72 + c8 * 8) = vk;
            bf16x8 vv = *(const bf16x8*)(vh + base + (size_t)(krow0 + r) * HD + c8 * 8);
            union { bf16x8 v; u16 s[8]; } uv; uv.v = vv;
#pragma unroll
            for (int j = 0; j < 8; j++) sVT[(c8 * 8 + j) * 40 + r] = uv.s[j];
        }
        __syncthreads();

        // ---- S = Q K^T for 2 halves of 16 cols ----
        float sv[2][4];
#pragma unroll
        for (int kc = 0; kc < 2; kc++) {
            bf16x8 b0 = *(const bf16x8*)(sK + (kc * 16 + l16) * 72 + quad * 8);
            bf16x8 b1 = *(const bf16x8*)(sK + (kc * 16 + l16) * 72 + 32 + quad * 8);
            f32x4 s = {};
            s = __builtin_amdgcn_mfma_f32_16x16x32_bf16(aq0, b0, s, 0, 0, 0);
            s = __builtin_amdgcn_mfma_f32_16x16x32_bf16(aq1, b1, s, 0, 0, 0);
            int kcol = krow0 + kc * 16 + l16;
#pragma unroll
            for (int r = 0; r < 4; r++) {
                int qrow = qbase + quad * 4 + r;
                float x = s[r] * scale;
                sv[kc][r] = (kcol > qrow) ? -INFINITY : x;
            }
        }
        // ---- online softmax ----
        float p[2][4];
#pragma unroll
        for (int r = 0; r < 4; r++) {
            float mx = fmaxf(sv[0][r], sv[1][r]);
#pragma unroll
            for (int off = 1; off < 16; off <<= 1) mx = fmaxf(mx, __shfl_xor(mx, off));
            float mnew = fmaxf(mrow[r], mx);
            float alpha = (mrow[r] == -INFINITY) ? 0.f : __expf(mrow[r] - mnew);
            float p0 = (sv[0][r] == -INFINITY) ? 0.f : __expf(sv[0][r] - mnew);
            float p1 = (sv[1][r] == -INFINITY) ? 0.f : __expf(sv[1][r] - mnew);
            float ts = p0 + p1;
#pragma unroll
            for (int off = 1; off < 16; off <<= 1) ts += __shfl_xor(ts, off);
            lrow[r] = lrow[r] * alpha + ts;
            mrow[r] = mnew;
            p[0][r] = p0; p[1][r] = p1;
#pragma unroll
            for (int nt = 0; nt < 4; nt++) o[nt][r] *= alpha;
        }
        // ---- P -> LDS (C-layout to A-layout round trip) ----
        u16* pw = sP + wave * 16 * 40;
#pragma unroll
        for (int kc = 0; kc < 2; kc++)
#pragma unroll
            for (int r = 0; r < 4; r++)
                pw[(quad * 4 + r) * 40 + kc * 16 + l16] = f2bf(p[kc][r]);
        // same-wave LDS ops are in-order; no barrier needed
        bf16x8 ap = *(const bf16x8*)(pw + l16 * 40 + quad * 8);
        // ---- O += P V ----
#pragma unroll
        for (int nt = 0; nt < 4; nt++) {
            bf16x8 bv = *(const bf16x8*)(sVT + (nt * 16 + l16) * 40 + quad * 8);
            o[nt] = __builtin_amdgcn_mfma_f32_16x16x32_bf16(ap, bv, o[nt], 0, 0, 0);
        }
        __syncthreads();
    }

    // ---- epilogue: normalize, write y[b*1024+l][h*64+d] ----
    const int b = bh >> 4, h = bh & 15;
#pragma unroll
    for (int nt = 0; nt < 4; nt++) {
#pragma unroll
        for (int r = 0; r < 4; r++) {
            int qrow = qbase + quad * 4 + r;
            int d = nt * 16 + l16;
            float val = o[nt][r] / lrow[r];
            y[(size_t)(b * 1024 + qrow) * 1024 + h * 64 + d] = f2bf(val);
        }
    }
}

extern "C" void kernel_launch(void* const* d_in, const int* in_sizes, int n_in,
                              void* d_out, int out_size, void* d_ws, size_t ws_size,
                              hipStream_t stream)
{
    const float* key   = (const float*)d_in[0];
    const float* value = (const float*)d_in[1];
    const float* query = (const float*)d_in[2];
    const float* Wk = (const float*)d_in[3];
    const float* bk = (const float*)d_in[4];
    const float* Wq = (const float*)d_in[5];
    const float* bq = (const float*)d_in[6];
    const float* Wv = (const float*)d_in[7];
    const float* bv = (const float*)d_in[8];
    const float* Wp = (const float*)d_in[9];
    const float* bp = (const float*)d_in[10];

    const int M = 4096, N = 1024, K = 1024;
    const size_t HEADS_ELEMS = (size_t)4 * 16 * 1024 * 64;   // 4,194,304
    u16* qh = (u16*)d_ws;
    u16* kh = qh + HEADS_ELEMS;
    u16* vh = kh + HEADS_ELEMS;
    u16* y  = vh + HEADS_ELEMS;

    dim3 grid(N / 128, M / 128), blk(256);
    hipLaunchKernelGGL((gemm_nt<true, 0>), grid, blk, 0, stream,
                       (const void*)query, Wq, bq, (void*)qh, M, N, K);
    hipLaunchKernelGGL((gemm_nt<true, 0>), grid, blk, 0, stream,
                       (const void*)key, Wk, bk, (void*)kh, M, N, K);
    hipLaunchKernelGGL((gemm_nt<true, 0>), grid, blk, 0, stream,
                       (const void*)value, Wv, bv, (void*)vh, M, N, K);
    hipLaunchKernelGGL(attn_kernel, dim3(4 * 16 * 16), blk, 0, stream, qh, kh, vh, y);
    hipLaunchKernelGGL((gemm_nt<false, 1>), grid, blk, 0, stream,
                       (const void*)y, Wp, bp, d_out, M, N, K);
}

// Round 2
// 226.898 us; speedup vs baseline: 1.7644x; 1.7644x over previous
//
#include <hip/hip_runtime.h>

typedef unsigned short u16;
typedef __attribute__((ext_vector_type(8))) short bf16x8;
typedef __attribute__((ext_vector_type(4))) float f32x4;
typedef __attribute__((ext_vector_type(4))) unsigned short u16x4;

#define MFMA16 __builtin_amdgcn_mfma_f32_16x16x32_bf16

__device__ inline u16 f2bf(float f) {
    union { float f; unsigned u; } v; v.f = f;
    unsigned r = v.u + 0x7fffu + ((v.u >> 16) & 1u);   // RTNE
    return (u16)(r >> 16);
}

// async global->LDS, 16 bytes per lane. LDS dest must be wave-uniform base + lane*16.
__device__ inline void gld16(const u16* g, u16* l) {
    __builtin_amdgcn_global_load_lds(
        (const __attribute__((address_space(1))) unsigned int*)g,
        (__attribute__((address_space(3))) unsigned int*)l, 16, 0, 0);
}

// ---------------- fp32 -> bf16 conversion (activations + weights) ----------------
struct CvtArgs { const float* src[7]; u16* dst[7]; };

__global__ __launch_bounds__(256) void cvt_kernel(CvtArgs a) {
    const int z = blockIdx.z;
    const int n = (z < 3) ? 4194304 : 1048576;
    const size_t i = ((size_t)blockIdx.x * 256 + threadIdx.x) * 8;
    if (i >= (size_t)n) return;
    const float* s = a.src[z];
    float4 v0 = *(const float4*)(s + i);
    float4 v1 = *(const float4*)(s + i + 4);
    union { u16 h[8]; bf16x8 v; } o;
    o.h[0] = f2bf(v0.x); o.h[1] = f2bf(v0.y); o.h[2] = f2bf(v0.z); o.h[3] = f2bf(v0.w);
    o.h[4] = f2bf(v1.x); o.h[5] = f2bf(v1.y); o.h[6] = f2bf(v1.z); o.h[7] = f2bf(v1.w);
    *(bf16x8*)(a.dst[z] + i) = o.v;
}

// ---------------- bf16 NT GEMM: C[m,n] = sum_k A[m,k]*W[n,k] + bias[n] ----------------
// tile 128x64, BK=64, glds staging into XOR-swizzled LDS (16B unit ^ (row&7)).
// epi 0: bf16 out[((b*16+h)*1024+l)*64+hd]   (head-split, for Q/K)
// epi 2: bf16 out[((b*16+h)*64+hd)*1024+l]   (head-split transposed, for V)
// epi 1: fp32 out[m*1024+n]
struct GemmArgs { const u16* A; const u16* W; const float* bias; void* out; int epi; };
struct Gemm3Args { GemmArgs g[3]; };

__global__ __launch_bounds__(256, 2) void gemm_bt(Gemm3Args ga) {
    constexpr int K = 1024;
    __shared__ u16 lA[128 * 64];
    __shared__ u16 lB[64 * 64];
    const GemmArgs g = ga.g[blockIdx.z];
    const int t = threadIdx.x, wave = t >> 6, lane = t & 63;
    const int quad = lane >> 4, l16 = lane & 15;
    const int mt = blockIdx.y, ntile = blockIdx.x;
    const int rowsA = mt * 128, rowsB = ntile * 64;
    const int wm = (wave >> 1) * 64, wn = (wave & 1) * 32;
    const u16* A = g.A; const u16* W = g.W;

    f32x4 acc[4][2] = {};

    for (int kb = 0; kb < K; kb += 64) {
#pragma unroll
        for (int i = 0; i < 4; i++) {
            int u = (i * 4 + wave) * 64 + lane;
            int row = u >> 3, cu = (u & 7) ^ (row & 7);
            gld16(A + (size_t)(rowsA + row) * K + kb + cu * 8, lA + u * 8);
        }
#pragma unroll
        for (int i = 0; i < 2; i++) {
            int u = (i * 4 + wave) * 64 + lane;
            int row = u >> 3, cu = (u & 7) ^ (row & 7);
            gld16(W + (size_t)(rowsB + row) * K + kb + cu * 8, lB + u * 8);
        }
        __syncthreads();

        bf16x8 af[4][2], bfr[2][2];
#pragma unroll
        for (int mi = 0; mi < 4; mi++) {
            int row = wm + mi * 16 + l16;
#pragma unroll
            for (int kr = 0; kr < 2; kr++)
                af[mi][kr] = *(const bf16x8*)(lA + row * 64 + (((kr * 4 + quad) ^ (row & 7)) * 8));
        }
#pragma unroll
        for (int ni = 0; ni < 2; ni++) {
            int row = wn + ni * 16 + l16;
#pragma unroll
            for (int kr = 0; kr < 2; kr++)
                bfr[ni][kr] = *(const bf16x8*)(lB + row * 64 + (((kr * 4 + quad) ^ (row & 7)) * 8));
        }
#pragma unroll
        for (int mi = 0; mi < 4; mi++)
#pragma unroll
            for (int ni = 0; ni < 2; ni++) {
                acc[mi][ni] = MFMA16(af[mi][0], bfr[ni][0], acc[mi][ni], 0, 0, 0);
                acc[mi][ni] = MFMA16(af[mi][1], bfr[ni][1], acc[mi][ni], 0, 0, 0);
            }
        __syncthreads();
    }

    const int epi = g.epi;
#pragma unroll
    for (int ni = 0; ni < 2; ni++) {
        const int ncol = rowsB + wn + ni * 16 + l16;
        const float bv = g.bias[ncol];
        const int h = ncol >> 6, hd = ncol & 63;
#pragma unroll
        for (int mi = 0; mi < 4; mi++) {
            const int mrow0 = rowsA + wm + mi * 16 + quad * 4;
            const int b = mrow0 >> 10, l0 = mrow0 & 1023;
            if (epi == 0) {
#pragma unroll
                for (int r = 0; r < 4; r++)
                    ((u16*)g.out)[((size_t)(b * 16 + h) * 1024 + l0 + r) * 64 + hd] =
                        f2bf(acc[mi][ni][r] + bv);
            } else if (epi == 2) {
                u16x4 pk;
#pragma unroll
                for (int r = 0; r < 4; r++) pk[r] = f2bf(acc[mi][ni][r] + bv);
                *(u16x4*)((u16*)g.out + ((size_t)(b * 16 + h) * 64 + hd) * 1024 + l0) = pk;
            } else {
#pragma unroll
                for (int r = 0; r < 4; r++)
                    ((float*)g.out)[(size_t)(mrow0 + r) * 1024 + ncol] = acc[mi][ni][r] + bv;
            }
        }
    }
}

// ---------------- flash attention ----------------
// grid = 64 heads * 8 qtiles; block 256 = 4 waves; wave owns 32 q rows (2 frags).
// K-tile = 64 rows. sK/sVT glds-staged with XOR swizzle. Row-sum via MFMA w/ ones.
__global__ __launch_bounds__(256, 2) void attn_kernel(const u16* __restrict__ qh,
                                                      const u16* __restrict__ kh,
                                                      const u16* __restrict__ vhT,
                                                      u16* __restrict__ y)
{
    __shared__ u16 sK[64 * 64];
    __shared__ u16 sVT[64 * 64];
    __shared__ u16 sP[4 * 32 * 72];

    const int t = threadIdx.x, wave = t >> 6, lane = t & 63;
    const int quad = lane >> 4, l16 = lane & 15;
    const int bid = blockIdx.x, qt = bid & 7, bh = bid >> 3;
    const size_t base = (size_t)bh * 1024 * 64;
    const int qoff = qt * 128 + wave * 32;
    const int qmax = qoff + 31;

    bf16x8 aq[2][2];
#pragma unroll
    for (int qf = 0; qf < 2; qf++)
#pragma unroll
        for (int kr = 0; kr < 2; kr++)
            aq[qf][kr] = *(const bf16x8*)(qh + base + (size_t)(qoff + qf * 16 + l16) * 64 + kr * 32 + quad * 8);

    bf16x8 ones;
#pragma unroll
    for (int j = 0; j < 8; j++) ones[j] = (short)0x3F80;

    f32x4 o[2][4] = {};
    f32x4 lacc[2] = {};
    float m[2][4];
#pragma unroll
    for (int qf = 0; qf < 2; qf++)
#pragma unroll
        for (int r = 0; r < 4; r++) m[qf][r] = -__builtin_inff();

    const int nkt = 2 * qt + 2;
    const float scale = 0.125f;

    for (int kb = 0; kb < nkt; kb++) {
        const int krow0 = kb * 64;
        // stage K [64 krow][64 d] and V^T [64 d][64 krow]
#pragma unroll
        for (int i = 0; i < 2; i++) {
            int u = (i * 4 + wave) * 64 + lane;
            int row = u >> 3, cu = (u & 7) ^ (row & 7);
            gld16(kh + base + (size_t)(krow0 + row) * 64 + cu * 8, sK + u * 8);
        }
#pragma unroll
        for (int i = 0; i < 2; i++) {
            int u = (i * 4 + wave) * 64 + lane;
            int row = u >> 3, cu = (u & 7) ^ (row & 7);
            gld16(vhT + ((size_t)(bh * 64 + row)) * 1024 + krow0 + cu * 8, sVT + u * 8);
        }
        __syncthreads();

        if (krow0 <= qmax) {
            bf16x8 bk[4][2];
#pragma unroll
            for (int kc = 0; kc < 4; kc++) {
                int row = kc * 16 + l16;
#pragma unroll
                for (int kr = 0; kr < 2; kr++)
                    bk[kc][kr] = *(const bf16x8*)(sK + row * 64 + (((kr * 4 + quad) ^ (row & 7)) * 8));
            }
#pragma unroll
            for (int qf = 0; qf < 2; qf++) {
                f32x4 s[4];
#pragma unroll
                for (int kc = 0; kc < 4; kc++) {
                    f32x4 z = {};
                    z = MFMA16(aq[qf][0], bk[kc][0], z, 0, 0, 0);
                    z = MFMA16(aq[qf][1], bk[kc][1], z, 0, 0, 0);
                    s[kc] = z;
                }
                const bool domask = (krow0 + 63 > qoff + qf * 16);
#pragma unroll
                for (int kc = 0; kc < 4; kc++)
#pragma unroll
                    for (int r = 0; r < 4; r++) {
                        float x = s[kc][r] * scale;
                        if (domask) {
                            int kcol = krow0 + kc * 16 + l16;
                            int qrow = qoff + qf * 16 + quad * 4 + r;
                            x = (kcol > qrow) ? -__builtin_inff() : x;
                        }
                        s[kc][r] = x;
                    }
                u16* pw = sP + (wave * 32 + qf * 16) * 72;
#pragma unroll
                for (int r = 0; r < 4; r++) {
                    float mloc = fmaxf(fmaxf(s[0][r], s[1][r]), fmaxf(s[2][r], s[3][r]));
#pragma unroll
                    for (int off = 1; off < 16; off <<= 1)
                        mloc = fmaxf(mloc, __shfl_xor(mloc, off));
                    float mn = fmaxf(m[qf][r], mloc);
                    float alpha = __expf(m[qf][r] - mn);
                    m[qf][r] = mn;
#pragma unroll
                    for (int kc = 0; kc < 4; kc++) {
                        float p = __expf(s[kc][r] - mn);
                        pw[(quad * 4 + r) * 72 + kc * 16 + l16] = f2bf(p);
                    }
#pragma unroll
                    for (int nt = 0; nt < 4; nt++) o[qf][nt][r] *= alpha;
                    lacc[qf][r] *= alpha;
                }
            }
            // PV
            bf16x8 bv[4][2];
#pragma unroll
            for (int nt = 0; nt < 4; nt++) {
                int row = nt * 16 + l16;
#pragma unroll
                for (int kr = 0; kr < 2; kr++)
                    bv[nt][kr] = *(const bf16x8*)(sVT + row * 64 + (((kr * 4 + quad) ^ (row & 7)) * 8));
            }
#pragma unroll
            for (int qf = 0; qf < 2; qf++) {
                const u16* pw = sP + (wave * 32 + qf * 16) * 72;
                bf16x8 ap0 = *(const bf16x8*)(pw + l16 * 72 + quad * 8);
                bf16x8 ap1 = *(const bf16x8*)(pw + l16 * 72 + 32 + quad * 8);
#pragma unroll
                for (int nt = 0; nt < 4; nt++) {
                    o[qf][nt] = MFMA16(ap0, bv[nt][0], o[qf][nt], 0, 0, 0);
                    o[qf][nt] = MFMA16(ap1, bv[nt][1], o[qf][nt], 0, 0, 0);
                }
                lacc[qf] = MFMA16(ap0, ones, lacc[qf], 0, 0, 0);
                lacc[qf] = MFMA16(ap1, ones, lacc[qf], 0, 0, 0);
            }
        }
        __syncthreads();
    }

    const int b = bh >> 4, h = bh & 15;
#pragma unroll
    for (int qf = 0; qf < 2; qf++)
#pragma unroll
        for (int nt = 0; nt < 4; nt++)
#pragma unroll
            for (int r = 0; r < 4; r++) {
                int qrow = qoff + qf * 16 + quad * 4 + r;
                int d = nt * 16 + l16;
                y[(size_t)(b * 1024 + qrow) * 1024 + h * 64 + d] = f2bf(o[qf][nt][r] / lacc[qf][r]);
            }
}

extern "C" void kernel_launch(void* const* d_in, const int* in_sizes, int n_in,
                              void* d_out, int out_size, void* d_ws, size_t ws_size,
                              hipStream_t stream)
{
    const float* key   = (const float*)d_in[0];
    const float* value = (const float*)d_in[1];
    const float* query = (const float*)d_in[2];
    const float* Wk = (const float*)d_in[3];
    const float* bk = (const float*)d_in[4];
    const float* Wq = (const float*)d_in[5];
    const float* bq = (const float*)d_in[6];
    const float* Wv = (const float*)d_in[7];
    const float* bv = (const float*)d_in[8];
    const float* Wp = (const float*)d_in[9];
    const float* bp = (const float*)d_in[10];

    char* ws = (char*)d_ws;
    u16* xq  = (u16*)(ws + (size_t)( 0 << 20));
    u16* xk  = (u16*)(ws + (size_t)( 8 << 20));
    u16* xv  = (u16*)(ws + (size_t)(16 << 20));
    u16* wqb = (u16*)(ws + (size_t)(24 << 20));
    u16* wkb = (u16*)(ws + (size_t)(26 << 20));
    u16* wvb = (u16*)(ws + (size_t)(28 << 20));
    u16* wpb = (u16*)(ws + (size_t)(30 << 20));
    u16* qh  = (u16*)(ws + (size_t)(32 << 20));
    u16* kh  = (u16*)(ws + (size_t)(40 << 20));
    u16* vhT = (u16*)(ws + (size_t)(48 << 20));
    u16* y   = xq;   // xq is dead after the QKV GEMM

    CvtArgs ca;
    ca.src[0] = query; ca.dst[0] = xq;
    ca.src[1] = key;   ca.dst[1] = xk;
    ca.src[2] = value; ca.dst[2] = xv;
    ca.src[3] = Wq;    ca.dst[3] = wqb;
    ca.src[4] = Wk;    ca.dst[4] = wkb;
    ca.src[5] = Wv;    ca.dst[5] = wvb;
    ca.src[6] = Wp;    ca.dst[6] = wpb;
    hipLaunchKernelGGL(cvt_kernel, dim3(2048, 1, 7), dim3(256), 0, stream, ca);

    Gemm3Args g3;
    g3.g[0] = GemmArgs{xq, wqb, bq, (void*)qh,  0};
    g3.g[1] = GemmArgs{xk, wkb, bk, (void*)kh,  0};
    g3.g[2] = GemmArgs{xv, wvb, bv, (void*)vhT, 2};
    hipLaunchKernelGGL(gemm_bt, dim3(16, 32, 3), dim3(256), 0, stream, g3);

    hipLaunchKernelGGL(attn_kernel, dim3(512), dim3(256), 0, stream, qh, kh, vhT, y);

    Gemm3Args gp;
    gp.g[0] = GemmArgs{y, wpb, bp, d_out, 1};
    gp.g[1] = gp.g[0]; gp.g[2] = gp.g[0];
    hipLaunchKernelGGL(gemm_bt, dim3(16, 32, 1), dim3(256), 0, stream, gp);
}

// Round 3
// 211.923 us; speedup vs baseline: 1.8891x; 1.0707x over previous
//
#include <hip/hip_runtime.h>

typedef unsigned short u16;
typedef __attribute__((ext_vector_type(8))) short bf16x8;
typedef __attribute__((ext_vector_type(4))) float f32x4;
typedef __attribute__((ext_vector_type(4))) unsigned short u16x4;

#define MFMA16 __builtin_amdgcn_mfma_f32_16x16x32_bf16

__device__ inline u16 f2bf(float f) {
    union { float f; unsigned u; } v; v.f = f;
    unsigned r = v.u + 0x7fffu + ((v.u >> 16) & 1u);   // RTNE
    return (u16)(r >> 16);
}

// async global->LDS, 16 bytes per lane. LDS dest = wave-uniform base + lane*16.
__device__ inline void gld16(const u16* g, u16* l) {
    __builtin_amdgcn_global_load_lds(
        (const __attribute__((address_space(1))) unsigned int*)g,
        (__attribute__((address_space(3))) unsigned int*)l, 16, 0, 0);
}

// ---------------- fp32 -> bf16 conversion ----------------
struct CvtArgs { const float* src[7]; u16* dst[7]; };

__global__ __launch_bounds__(256) void cvt_kernel(CvtArgs a) {
    const int z = blockIdx.z;
    const int n = (z < 3) ? 4194304 : 1048576;
    const size_t i = ((size_t)blockIdx.x * 256 + threadIdx.x) * 8;
    if (i >= (size_t)n) return;
    const float* s = a.src[z];
    float4 v0 = *(const float4*)(s + i);
    float4 v1 = *(const float4*)(s + i + 4);
    union { u16 h[8]; bf16x8 v; } o;
    o.h[0] = f2bf(v0.x); o.h[1] = f2bf(v0.y); o.h[2] = f2bf(v0.z); o.h[3] = f2bf(v0.w);
    o.h[4] = f2bf(v1.x); o.h[5] = f2bf(v1.y); o.h[6] = f2bf(v1.z); o.h[7] = f2bf(v1.w);
    *(bf16x8*)(a.dst[z] + i) = o.v;
}

// ---------------- bf16 NT GEMM, 128x128 tile, BK=32 (m97 structure) ----------------
// C[m,n] = sum_k A[m,k]*W[n,k] + bias[n]
// epi 0: bf16 out[((b*16+h)*1024+l)*64+hd]    (head-split, Q/K)
// epi 2: bf16 out[((b*16+h)*64+hd)*1024+l]    (head-split transposed, V)
// epi 1: fp32 out[m*1024+n]
struct GemmArgs { const u16* A; const u16* W; const float* bias; void* out; int epi; };
struct Gemm3Args { GemmArgs g[3]; };

__global__ __launch_bounds__(256, 2) void gemm_bt(Gemm3Args ga) {
    __shared__ u16 lA[128 * 32];
    __shared__ u16 lB[128 * 32];
    const GemmArgs g = ga.g[blockIdx.z];
    const int t = threadIdx.x, wave = t >> 6, lane = t & 63;
    const int quad = lane >> 4, l16 = lane & 15;
    const int rowsA = blockIdx.y * 128, rowsB = blockIdx.x * 128;
    const int wm = (wave >> 1) * 64, wn = (wave & 1) * 64;
    const u16* A = g.A; const u16* W = g.W;

    f32x4 acc[4][4] = {};

    for (int kb = 0; kb < 1024; kb += 32) {
#pragma unroll
        for (int i = 0; i < 2; i++) {
            int u = (i * 4 + wave) * 64 + lane;
            int row = u >> 2, cu = (u & 3) ^ (row & 3);
            gld16(A + (size_t)(rowsA + row) * 1024 + kb + cu * 8, lA + u * 8);
        }
#pragma unroll
        for (int i = 0; i < 2; i++) {
            int u = (i * 4 + wave) * 64 + lane;
            int row = u >> 2, cu = (u & 3) ^ (row & 3);
            gld16(W + (size_t)(rowsB + row) * 1024 + kb + cu * 8, lB + u * 8);
        }
        __syncthreads();

        bf16x8 af[4], bfr[4];
#pragma unroll
        for (int mi = 0; mi < 4; mi++) {
            int row = wm + mi * 16 + l16;
            af[mi] = *(const bf16x8*)(lA + row * 32 + ((quad ^ (row & 3)) * 8));
        }
#pragma unroll
        for (int ni = 0; ni < 4; ni++) {
            int row = wn + ni * 16 + l16;
            bfr[ni] = *(const bf16x8*)(lB + row * 32 + ((quad ^ (row & 3)) * 8));
        }
#pragma unroll
        for (int mi = 0; mi < 4; mi++)
#pragma unroll
            for (int ni = 0; ni < 4; ni++)
                acc[mi][ni] = MFMA16(af[mi], bfr[ni], acc[mi][ni], 0, 0, 0);
        __syncthreads();
    }

    const int epi = g.epi;
#pragma unroll
    for (int ni = 0; ni < 4; ni++) {
        const int ncol = rowsB + wn + ni * 16 + l16;
        const float bv = g.bias[ncol];
        const int h = ncol >> 6, hd = ncol & 63;
#pragma unroll
        for (int mi = 0; mi < 4; mi++) {
            const int mrow0 = rowsA + wm + mi * 16 + quad * 4;
            const int b = mrow0 >> 10, l0 = mrow0 & 1023;
            if (epi == 0) {
#pragma unroll
                for (int r = 0; r < 4; r++)
                    ((u16*)g.out)[((size_t)(b * 16 + h) * 1024 + l0 + r) * 64 + hd] =
                        f2bf(acc[mi][ni][r] + bv);
            } else if (epi == 2) {
                u16x4 pk;
#pragma unroll
                for (int r = 0; r < 4; r++) pk[r] = f2bf(acc[mi][ni][r] + bv);
                *(u16x4*)((u16*)g.out + ((size_t)(b * 16 + h) * 64 + hd) * 1024 + l0) = pk;
            } else {
#pragma unroll
                for (int r = 0; r < 4; r++)
                    ((float*)g.out)[(size_t)(mrow0 + r) * 1024 + ncol] = acc[mi][ni][r] + bv;
            }
        }
    }
}

// ---------------- flash attention, paired q-tiles, no online max ----------------
// grid (8 pairs, 64 heads); block 256 = 4 waves; q-tile = 64 rows (16/wave).
// Block handles qt in {15-p, p}; both share each staged 64-row K/V tile.
__global__ __launch_bounds__(256) void attn_kernel(const u16* __restrict__ qh,
                                                   const u16* __restrict__ kh,
                                                   const u16* __restrict__ vhT,
                                                   u16* __restrict__ y)
{
    __shared__ u16 sK[64 * 64];
    __shared__ u16 sVT[64 * 64];
    __shared__ u16 sP[4 * 16 * 72];

    const int t = threadIdx.x, wave = t >> 6, lane = t & 63;
    const int quad = lane >> 4, l16 = lane & 15;
    const int p = blockIdx.x, bh = blockIdx.y;
    const int qt0 = 15 - p, qt1 = p;              // long tile first
    const size_t base = (size_t)bh * 1024 * 64;
    const float scale = 0.125f;

    bf16x8 aq[2][2];
#pragma unroll
    for (int s = 0; s < 2; s++) {
        const int qoff = (s == 0 ? qt0 : qt1) * 64 + wave * 16;
#pragma unroll
        for (int kr = 0; kr < 2; kr++)
            aq[s][kr] = *(const bf16x8*)(qh + base + (size_t)(qoff + l16) * 64 + kr * 32 + quad * 8);
    }

    bf16x8 ones;
#pragma unroll
    for (int j = 0; j < 8; j++) ones[j] = (short)0x3F80;

    f32x4 o[2][4] = {};
    f32x4 lacc[2] = {};
    u16* pw = sP + wave * 16 * 72;

    for (int kb = 0; kb <= qt0; kb++) {
        const int krow0 = kb * 64;
        // stage K [64 krow][64 d] and V^T [64 d][64 krow]
#pragma unroll
        for (int i = 0; i < 2; i++) {
            int u = (i * 4 + wave) * 64 + lane;
            int row = u >> 3, cu = (u & 7) ^ (row & 7);
            gld16(kh + base + (size_t)(krow0 + row) * 64 + cu * 8, sK + u * 8);
        }
#pragma unroll
        for (int i = 0; i < 2; i++) {
            int u = (i * 4 + wave) * 64 + lane;
            int row = u >> 3, cu = (u & 7) ^ (row & 7);
            gld16(vhT + ((size_t)(bh * 64 + row)) * 1024 + krow0 + cu * 8, sVT + u * 8);
        }
        __syncthreads();

        // fragments read once, shared by both q-tiles
        bf16x8 bk[4][2], bv[4][2];
#pragma unroll
        for (int kc = 0; kc < 4; kc++) {
            int row = kc * 16 + l16;
#pragma unroll
            for (int kr = 0; kr < 2; kr++)
                bk[kc][kr] = *(const bf16x8*)(sK + row * 64 + (((kr * 4 + quad) ^ (row & 7)) * 8));
        }
#pragma unroll
        for (int nt = 0; nt < 4; nt++) {
            int row = nt * 16 + l16;
#pragma unroll
            for (int kr = 0; kr < 2; kr++)
                bv[nt][kr] = *(const bf16x8*)(sVT + row * 64 + (((kr * 4 + quad) ^ (row & 7)) * 8));
        }

        auto compute = [&](int s, int qtv) {
            const int qoff = qtv * 64 + wave * 16;
            f32x4 sc[4];
#pragma unroll
            for (int kc = 0; kc < 4; kc++) {
                f32x4 z = {};
                z = MFMA16(aq[s][0], bk[kc][0], z, 0, 0, 0);
                z = MFMA16(aq[s][1], bk[kc][1], z, 0, 0, 0);
                sc[kc] = z;
            }
            const bool diag = (kb == qtv);
#pragma unroll
            for (int kc = 0; kc < 4; kc++)
#pragma unroll
                for (int r = 0; r < 4; r++) {
                    float x = fminf(sc[kc][r] * scale, 30.f);
                    float pv = __expf(x);
                    if (diag) {
                        int kcol = krow0 + kc * 16 + l16;
                        int qrow = qoff + quad * 4 + r;
                        if (kcol > qrow) pv = 0.f;
                    }
                    pw[(quad * 4 + r) * 72 + kc * 16 + l16] = f2bf(pv);
                }
            bf16x8 ap0 = *(const bf16x8*)(pw + l16 * 72 + quad * 8);
            bf16x8 ap1 = *(const bf16x8*)(pw + l16 * 72 + 32 + quad * 8);
#pragma unroll
            for (int nt = 0; nt < 4; nt++) {
                o[s][nt] = MFMA16(ap0, bv[nt][0], o[s][nt], 0, 0, 0);
                o[s][nt] = MFMA16(ap1, bv[nt][1], o[s][nt], 0, 0, 0);
            }
            lacc[s] = MFMA16(ap0, ones, lacc[s], 0, 0, 0);
            lacc[s] = MFMA16(ap1, ones, lacc[s], 0, 0, 0);
        };

        compute(0, qt0);
        if (kb <= qt1) compute(1, qt1);
        __syncthreads();
    }

    const int b = bh >> 4, h = bh & 15;
#pragma unroll
    for (int s = 0; s < 2; s++) {
        const int qoff = (s == 0 ? qt0 : qt1) * 64 + wave * 16;
#pragma unroll
        for (int nt = 0; nt < 4; nt++)
#pragma unroll
            for (int r = 0; r < 4; r++) {
                int qrow = qoff + quad * 4 + r;
                int d = nt * 16 + l16;
                y[(size_t)(b * 1024 + qrow) * 1024 + h * 64 + d] =
                    f2bf(o[s][nt][r] / lacc[s][r]);
            }
    }
}

extern "C" void kernel_launch(void* const* d_in, const int* in_sizes, int n_in,
                              void* d_out, int out_size, void* d_ws, size_t ws_size,
                              hipStream_t stream)
{
    const float* key   = (const float*)d_in[0];
    const float* value = (const float*)d_in[1];
    const float* query = (const float*)d_in[2];
    const float* Wk = (const float*)d_in[3];
    const float* bk = (const float*)d_in[4];
    const float* Wq = (const float*)d_in[5];
    const float* bq = (const float*)d_in[6];
    const float* Wv = (const float*)d_in[7];
    const float* bv = (const float*)d_in[8];
    const float* Wp = (const float*)d_in[9];
    const float* bp = (const float*)d_in[10];

    char* ws = (char*)d_ws;
    u16* xq  = (u16*)(ws + (size_t)( 0 << 20));
    u16* xk  = (u16*)(ws + (size_t)( 8 << 20));
    u16* xv  = (u16*)(ws + (size_t)(16 << 20));
    u16* wqb = (u16*)(ws + (size_t)(24 << 20));
    u16* wkb = (u16*)(ws + (size_t)(26 << 20));
    u16* wvb = (u16*)(ws + (size_t)(28 << 20));
    u16* wpb = (u16*)(ws + (size_t)(30 << 20));
    u16* qh  = (u16*)(ws + (size_t)(32 << 20));
    u16* kh  = (u16*)(ws + (size_t)(40 << 20));
    u16* vhT = (u16*)(ws + (size_t)(48 << 20));
    u16* y   = xq;   // xq is dead after the QKV GEMM

    CvtArgs ca;
    ca.src[0] = query; ca.dst[0] = xq;
    ca.src[1] = key;   ca.dst[1] = xk;
    ca.src[2] = value; ca.dst[2] = xv;
    ca.src[3] = Wq;    ca.dst[3] = wqb;
    ca.src[4] = Wk;    ca.dst[4] = wkb;
    ca.src[5] = Wv;    ca.dst[5] = wvb;
    ca.src[6] = Wp;    ca.dst[6] = wpb;
    hipLaunchKernelGGL(cvt_kernel, dim3(2048, 1, 7), dim3(256), 0, stream, ca);

    Gemm3Args g3;
    g3.g[0] = GemmArgs{xq, wqb, bq, (void*)qh,  0};
    g3.g[1] = GemmArgs{xk, wkb, bk, (void*)kh,  0};
    g3.g[2] = GemmArgs{xv, wvb, bv, (void*)vhT, 2};
    hipLaunchKernelGGL(gemm_bt, dim3(8, 32, 3), dim3(256), 0, stream, g3);

    hipLaunchKernelGGL(attn_kernel, dim3(8, 64), dim3(256), 0, stream, qh, kh, vhT, y);

    Gemm3Args gp;
    gp.g[0] = GemmArgs{y, wpb, bp, d_out, 1};
    gp.g[1] = gp.g[0]; gp.g[2] = gp.g[0];
    hipLaunchKernelGGL(gemm_bt, dim3(8, 32, 1), dim3(256), 0, stream, gp);
}

// Round 4
// 203.862 us; speedup vs baseline: 1.9638x; 1.0395x over previous
//
#include <hip/hip_runtime.h>

typedef unsigned short u16;
typedef __attribute__((ext_vector_type(8))) short bf16x8;
typedef __attribute__((ext_vector_type(4))) float f32x4;
typedef __attribute__((ext_vector_type(4))) unsigned short u16x4;

#define MFMA16 __builtin_amdgcn_mfma_f32_16x16x32_bf16

__device__ inline u16 f2bf(float f) {            // cheap round-half-up
    union { float f; unsigned u; } v; v.f = f;
    return (u16)((v.u + 0x8000u) >> 16);
}

// async global->LDS, 16 B/lane. LDS dest = wave-uniform base + lane*16.
__device__ inline void gld16(const u16* g, u16* l) {
    __builtin_amdgcn_global_load_lds(
        (const __attribute__((address_space(1))) unsigned int*)g,
        (__attribute__((address_space(3))) unsigned int*)l, 16, 0, 0);
}

// ---------------- fp32 -> bf16 conversion ----------------
struct CvtArgs { const float* src[7]; u16* dst[7]; };

__global__ __launch_bounds__(256) void cvt_kernel(CvtArgs a) {
    const int z = blockIdx.z;
    const int n = (z < 3) ? 4194304 : 1048576;
    const size_t i = ((size_t)blockIdx.x * 256 + threadIdx.x) * 8;
    if (i >= (size_t)n) return;
    const float* s = a.src[z];
    float4 v0 = *(const float4*)(s + i);
    float4 v1 = *(const float4*)(s + i + 4);
    union { u16 h[8]; bf16x8 v; } o;
    o.h[0] = f2bf(v0.x); o.h[1] = f2bf(v0.y); o.h[2] = f2bf(v0.z); o.h[3] = f2bf(v0.w);
    o.h[4] = f2bf(v1.x); o.h[5] = f2bf(v1.y); o.h[6] = f2bf(v1.z); o.h[7] = f2bf(v1.w);
    *(bf16x8*)(a.dst[z] + i) = o.v;
}

// ---------------- QKV GEMM: 128x128 tile, BK=64 ----------------
// C[m,n] = sum_k A[m,k]*W[n,k] + bias[n]
// epi 0: bf16 out[((b*16+h)*1024+l)*64+hd]   epi 2: bf16 out[((b*16+h)*64+hd)*1024+l]
struct GemmArgs { const u16* A; const u16* W; const float* bias; void* out; int epi; };
struct Gemm3Args { GemmArgs g[3]; };

__global__ __launch_bounds__(256, 3) void gemm_qkv(Gemm3Args ga) {
    __shared__ u16 lA[128 * 64];
    __shared__ u16 lB[128 * 64];
    const GemmArgs g = ga.g[blockIdx.z];
    const int t = threadIdx.x, wave = t >> 6, lane = t & 63;
    const int quad = lane >> 4, l16 = lane & 15;
    const int rowsA = blockIdx.y * 128, rowsB = blockIdx.x * 128;
    const int wm = (wave >> 1) * 64, wn = (wave & 1) * 64;
    const u16* A = g.A; const u16* W = g.W;

    f32x4 acc[4][4] = {};

    for (int kb = 0; kb < 1024; kb += 64) {
#pragma unroll
        for (int i = 0; i < 4; i++) {
            int u = (i * 4 + wave) * 64 + lane;
            int row = u >> 3, cu = (u & 7) ^ (row & 7);
            gld16(A + (size_t)(rowsA + row) * 1024 + kb + cu * 8, lA + u * 8);
        }
#pragma unroll
        for (int i = 0; i < 4; i++) {
            int u = (i * 4 + wave) * 64 + lane;
            int row = u >> 3, cu = (u & 7) ^ (row & 7);
            gld16(W + (size_t)(rowsB + row) * 1024 + kb + cu * 8, lB + u * 8);
        }
        __syncthreads();

        bf16x8 af[4][2], bfr[4][2];
#pragma unroll
        for (int mi = 0; mi < 4; mi++) {
            int row = wm + mi * 16 + l16;
#pragma unroll
            for (int kr = 0; kr < 2; kr++)
                af[mi][kr] = *(const bf16x8*)(lA + row * 64 + (((kr * 4 + quad) ^ (row & 7)) * 8));
        }
#pragma unroll
        for (int ni = 0; ni < 4; ni++) {
            int row = wn + ni * 16 + l16;
#pragma unroll
            for (int kr = 0; kr < 2; kr++)
                bfr[ni][kr] = *(const bf16x8*)(lB + row * 64 + (((kr * 4 + quad) ^ (row & 7)) * 8));
        }
#pragma unroll
        for (int mi = 0; mi < 4; mi++)
#pragma unroll
            for (int ni = 0; ni < 4; ni++) {
                acc[mi][ni] = MFMA16(af[mi][0], bfr[ni][0], acc[mi][ni], 0, 0, 0);
                acc[mi][ni] = MFMA16(af[mi][1], bfr[ni][1], acc[mi][ni], 0, 0, 0);
            }
        __syncthreads();
    }

    const int epi = g.epi;
#pragma unroll
    for (int ni = 0; ni < 4; ni++) {
        const int ncol = rowsB + wn + ni * 16 + l16;
        const float bv = g.bias[ncol];
        const int h = ncol >> 6, hd = ncol & 63;
#pragma unroll
        for (int mi = 0; mi < 4; mi++) {
            const int mrow0 = rowsA + wm + mi * 16 + quad * 4;
            const int b = mrow0 >> 10, l0 = mrow0 & 1023;
            if (epi == 0) {
#pragma unroll
                for (int r = 0; r < 4; r++)
                    ((u16*)g.out)[((size_t)(b * 16 + h) * 1024 + l0 + r) * 64 + hd] =
                        f2bf(acc[mi][ni][r] + bv);
            } else {
                u16x4 pk;
#pragma unroll
                for (int r = 0; r < 4; r++) pk[r] = f2bf(acc[mi][ni][r] + bv);
                *(u16x4*)((u16*)g.out + ((size_t)(b * 16 + h) * 64 + hd) * 1024 + l0) = pk;
            }
        }
    }
}

// ---------------- P GEMM: 128x64 tile, BK=64, fp32 out ----------------
__global__ __launch_bounds__(256, 2) void gemm_p(const u16* __restrict__ A,
                                                 const u16* __restrict__ W,
                                                 const float* __restrict__ bias,
                                                 float* __restrict__ out)
{
    __shared__ u16 lA[128 * 64];
    __shared__ u16 lB[64 * 64];
    const int t = threadIdx.x, wave = t >> 6, lane = t & 63;
    const int quad = lane >> 4, l16 = lane & 15;
    const int rowsA = blockIdx.y * 128, rowsB = blockIdx.x * 64;
    const int wm = (wave >> 1) * 64, wn = (wave & 1) * 32;

    f32x4 acc[4][2] = {};

    for (int kb = 0; kb < 1024; kb += 64) {
#pragma unroll
        for (int i = 0; i < 4; i++) {
            int u = (i * 4 + wave) * 64 + lane;
            int row = u >> 3, cu = (u & 7) ^ (row & 7);
            gld16(A + (size_t)(rowsA + row) * 1024 + kb + cu * 8, lA + u * 8);
        }
#pragma unroll
        for (int i = 0; i < 2; i++) {
            int u = (i * 4 + wave) * 64 + lane;
            int row = u >> 3, cu = (u & 7) ^ (row & 7);
            gld16(W + (size_t)(rowsB + row) * 1024 + kb + cu * 8, lB + u * 8);
        }
        __syncthreads();

        bf16x8 af[4][2], bfr[2][2];
#pragma unroll
        for (int mi = 0; mi < 4; mi++) {
            int row = wm + mi * 16 + l16;
#pragma unroll
            for (int kr = 0; kr < 2; kr++)
                af[mi][kr] = *(const bf16x8*)(lA + row * 64 + (((kr * 4 + quad) ^ (row & 7)) * 8));
        }
#pragma unroll
        for (int ni = 0; ni < 2; ni++) {
            int row = wn + ni * 16 + l16;
#pragma unroll
            for (int kr = 0; kr < 2; kr++)
                bfr[ni][kr] = *(const bf16x8*)(lB + row * 64 + (((kr * 4 + quad) ^ (row & 7)) * 8));
        }
#pragma unroll
        for (int mi = 0; mi < 4; mi++)
#pragma unroll
            for (int ni = 0; ni < 2; ni++) {
                acc[mi][ni] = MFMA16(af[mi][0], bfr[ni][0], acc[mi][ni], 0, 0, 0);
                acc[mi][ni] = MFMA16(af[mi][1], bfr[ni][1], acc[mi][ni], 0, 0, 0);
            }
        __syncthreads();
    }

#pragma unroll
    for (int ni = 0; ni < 2; ni++) {
        const int ncol = rowsB + wn + ni * 16 + l16;
        const float bv = bias[ncol];
#pragma unroll
        for (int mi = 0; mi < 4; mi++) {
            const int mrow0 = rowsA + wm + mi * 16 + quad * 4;
#pragma unroll
            for (int r = 0; r < 4; r++)
                out[(size_t)(mrow0 + r) * 1024 + ncol] = acc[mi][ni][r] + bv;
        }
    }
}

// ---------------- flash attention, paired q-tiles, no online max ----------------
__global__ __launch_bounds__(256) void attn_kernel(const u16* __restrict__ qh,
                                                   const u16* __restrict__ kh,
                                                   const u16* __restrict__ vhT,
                                                   u16* __restrict__ y)
{
    __shared__ u16 sK[64 * 64];
    __shared__ u16 sVT[64 * 64];
    __shared__ u16 sP[4 * 16 * 72];

    const int t = threadIdx.x, wave = t >> 6, lane = t & 63;
    const int quad = lane >> 4, l16 = lane & 15;
    const int p = blockIdx.x, bh = blockIdx.y;
    const int qt0 = 15 - p, qt1 = p;
    const size_t base = (size_t)bh * 1024 * 64;
    const float e2 = 0.18033688f;     // 0.125 * log2(e)

    bf16x8 aq[2][2];
#pragma unroll
    for (int s = 0; s < 2; s++) {
        const int qoff = (s == 0 ? qt0 : qt1) * 64 + wave * 16;
#pragma unroll
        for (int kr = 0; kr < 2; kr++)
            aq[s][kr] = *(const bf16x8*)(qh + base + (size_t)(qoff + l16) * 64 + kr * 32 + quad * 8);
    }

    bf16x8 ones;
#pragma unroll
    for (int j = 0; j < 8; j++) ones[j] = (short)0x3F80;

    f32x4 o[2][4] = {};
    f32x4 lacc[2] = {};
    u16* pw = sP + wave * 16 * 72;

    for (int kb = 0; kb <= qt0; kb++) {
        const int krow0 = kb * 64;
#pragma unroll
        for (int i = 0; i < 2; i++) {
            int u = (i * 4 + wave) * 64 + lane;
            int row = u >> 3, cu = (u & 7) ^ (row & 7);
            gld16(kh + base + (size_t)(krow0 + row) * 64 + cu * 8, sK + u * 8);
        }
#pragma unroll
        for (int i = 0; i < 2; i++) {
            int u = (i * 4 + wave) * 64 + lane;
            int row = u >> 3, cu = (u & 7) ^ (row & 7);
            gld16(vhT + ((size_t)(bh * 64 + row)) * 1024 + krow0 + cu * 8, sVT + u * 8);
        }
        __syncthreads();

        bf16x8 bk[4][2], bv[4][2];
#pragma unroll
        for (int kc = 0; kc < 4; kc++) {
            int row = kc * 16 + l16;
#pragma unroll
            for (int kr = 0; kr < 2; kr++)
                bk[kc][kr] = *(const bf16x8*)(sK + row * 64 + (((kr * 4 + quad) ^ (row & 7)) * 8));
        }
#pragma unroll
        for (int nt = 0; nt < 4; nt++) {
            int row = nt * 16 + l16;
#pragma unroll
            for (int kr = 0; kr < 2; kr++)
                bv[nt][kr] = *(const bf16x8*)(sVT + row * 64 + (((kr * 4 + quad) ^ (row & 7)) * 8));
        }

        auto compute = [&](int s, int qtv) {
            const int qoff = qtv * 64 + wave * 16;
            f32x4 sc[4];
#pragma unroll
            for (int kc = 0; kc < 4; kc++) {
                f32x4 z = {};
                z = MFMA16(aq[s][0], bk[kc][0], z, 0, 0, 0);
                z = MFMA16(aq[s][1], bk[kc][1], z, 0, 0, 0);
                sc[kc] = z;
            }
            const bool diag = (kb == qtv);
#pragma unroll
            for (int kc = 0; kc < 4; kc++)
#pragma unroll
                for (int r = 0; r < 4; r++) {
                    float x = fminf(sc[kc][r] * e2, 43.f);
                    float pv = exp2f(x);
                    if (diag) {
                        int kcol = krow0 + kc * 16 + l16;
                        int qrow = qoff + quad * 4 + r;
                        if (kcol > qrow) pv = 0.f;
                    }
                    pw[(quad * 4 + r) * 72 + kc * 16 + l16] = f2bf(pv);
                }
            bf16x8 ap0 = *(const bf16x8*)(pw + l16 * 72 + quad * 8);
            bf16x8 ap1 = *(const bf16x8*)(pw + l16 * 72 + 32 + quad * 8);
#pragma unroll
            for (int nt = 0; nt < 4; nt++) {
                o[s][nt] = MFMA16(ap0, bv[nt][0], o[s][nt], 0, 0, 0);
                o[s][nt] = MFMA16(ap1, bv[nt][1], o[s][nt], 0, 0, 0);
            }
            lacc[s] = MFMA16(ap0, ones, lacc[s], 0, 0, 0);
            lacc[s] = MFMA16(ap1, ones, lacc[s], 0, 0, 0);
        };

        compute(0, qt0);
        if (kb <= qt1) compute(1, qt1);
        __syncthreads();
    }

    const int b = bh >> 4, h = bh & 15;
#pragma unroll
    for (int s = 0; s < 2; s++) {
        const int qoff = (s == 0 ? qt0 : qt1) * 64 + wave * 16;
#pragma unroll
        for (int nt = 0; nt < 4; nt++)
#pragma unroll
            for (int r = 0; r < 4; r++) {
                int qrow = qoff + quad * 4 + r;
                int d = nt * 16 + l16;
                y[(size_t)(b * 1024 + qrow) * 1024 + h * 64 + d] =
                    f2bf(o[s][nt][r] / lacc[s][r]);
            }
    }
}

extern "C" void kernel_launch(void* const* d_in, const int* in_sizes, int n_in,
                              void* d_out, int out_size, void* d_ws, size_t ws_size,
                              hipStream_t stream)
{
    const float* key   = (const float*)d_in[0];
    const float* value = (const float*)d_in[1];
    const float* query = (const float*)d_in[2];
    const float* Wk = (const float*)d_in[3];
    const float* bk = (const float*)d_in[4];
    const float* Wq = (const float*)d_in[5];
    const float* bq = (const float*)d_in[6];
    const float* Wv = (const float*)d_in[7];
    const float* bv = (const float*)d_in[8];
    const float* Wp = (const float*)d_in[9];
    const float* bp = (const float*)d_in[10];

    char* ws = (char*)d_ws;
    u16* xq  = (u16*)(ws + (size_t)( 0 << 20));
    u16* xk  = (u16*)(ws + (size_t)( 8 << 20));
    u16* xv  = (u16*)(ws + (size_t)(16 << 20));
    u16* wqb = (u16*)(ws + (size_t)(24 << 20));
    u16* wkb = (u16*)(ws + (size_t)(26 << 20));
    u16* wvb = (u16*)(ws + (size_t)(28 << 20));
    u16* wpb = (u16*)(ws + (size_t)(30 << 20));
    u16* qh  = (u16*)(ws + (size_t)(32 << 20));
    u16* kh  = (u16*)(ws + (size_t)(40 << 20));
    u16* vhT = (u16*)(ws + (size_t)(48 << 20));
    u16* y   = xq;   // xq dead after QKV GEMM

    CvtArgs ca;
    ca.src[0] = query; ca.dst[0] = xq;
    ca.src[1] = key;   ca.dst[1] = xk;
    ca.src[2] = value; ca.dst[2] = xv;
    ca.src[3] = Wq;    ca.dst[3] = wqb;
    ca.src[4] = Wk;    ca.dst[4] = wkb;
    ca.src[5] = Wv;    ca.dst[5] = wvb;
    ca.src[6] = Wp;    ca.dst[6] = wpb;
    hipLaunchKernelGGL(cvt_kernel, dim3(2048, 1, 7), dim3(256), 0, stream, ca);

    Gemm3Args g3;
    g3.g[0] = GemmArgs{xq, wqb, bq, (void*)qh,  0};
    g3.g[1] = GemmArgs{xk, wkb, bk, (void*)kh,  0};
    g3.g[2] = GemmArgs{xv, wvb, bv, (void*)vhT, 2};
    hipLaunchKernelGGL(gemm_qkv, dim3(8, 32, 3), dim3(256), 0, stream, g3);

    hipLaunchKernelGGL(attn_kernel, dim3(8, 64), dim3(256), 0, stream, qh, kh, vhT, y);

    hipLaunchKernelGGL(gemm_p, dim3(16, 32), dim3(256), 0, stream, y, wpb, bp, (float*)d_out);
}